// Round 1
// baseline (75.321 us; speedup 1.0000x reference)
//
#include <hip/hip_runtime.h>
#include <math.h>

#define B_ROWS 8192
#define D_DIM 512
#define N_LABELS 256

// ---------------- bucketing (deterministic, no atomics) ----------------

// One wave (64 threads) per label: count matching rows via ballot.
__global__ __launch_bounds__(64) void count_kernel(const int* __restrict__ Mx,
                                                   int* __restrict__ counts) {
    const int label = blockIdx.x;
    const int lane  = threadIdx.x;
    int cnt = 0;
    for (int base = 0; base < B_ROWS; base += 64) {
        const int m = Mx[base + lane];
        const unsigned long long bal = __ballot(m == label);
        cnt += __popcll(bal);
    }
    if (lane == 0) counts[label] = cnt;
}

// Single-thread exclusive prefix sum over 256 counts (trivial size).
__global__ __launch_bounds__(64) void scan_kernel(const int* __restrict__ counts,
                                                  int* __restrict__ offsets) {
    if (threadIdx.x == 0 && blockIdx.x == 0) {
        int acc = 0;
        for (int l = 0; l < N_LABELS; ++l) {
            offsets[l] = acc;
            acc += counts[l];
        }
    }
}

// One wave per label: scatter row indices into the label's bucket slice,
// in ascending row order (ballot + popcount of lower lanes).
__global__ __launch_bounds__(64) void fill_kernel(const int* __restrict__ Mx,
                                                  const int* __restrict__ offsets,
                                                  int* __restrict__ bucket) {
    const int label = blockIdx.x;
    const int lane  = threadIdx.x;
    int pos = offsets[label];
    const unsigned long long lower = (lane == 0) ? 0ull : ((1ull << lane) - 1ull);
    for (int base = 0; base < B_ROWS; base += 64) {
        const bool match = (Mx[base + lane] == label);
        const unsigned long long bal = __ballot(match);
        if (match) {
            const int rank = __popcll(bal & lower);
            bucket[pos + rank] = base + lane;
        }
        pos += __popcll(bal);
    }
}

// ---------------- main loss kernel ----------------
// One wave per row, rows walked in bucket order (adjacent waves share a label
// -> same partner set -> cache locality). Lane l owns elements [8l, 8l+8).

__global__ __launch_bounds__(256) void loss_kernel(const float* __restrict__ z,
                                                   const int* __restrict__ Mx,
                                                   const int* __restrict__ counts,
                                                   const int* __restrict__ offsets,
                                                   const int* __restrict__ bucket,
                                                   float* __restrict__ out) {
    const int wave = (int)((blockIdx.x * blockDim.x + threadIdx.x) >> 6);
    const int lane = threadIdx.x & 63;
    if (wave >= B_ROWS) return;

    const int i     = bucket[wave];          // row handled by this wave
    const int label = Mx[i];
    const int off   = offsets[label];
    const int cnt   = counts[label];

    const float* zi = z + (size_t)i * D_DIM + lane * 8;
    const float4 a0 = *(const float4*)(zi);
    const float4 a1 = *(const float4*)(zi + 4);

    float acc = 0.0f;
    for (int k = 0; k < cnt; ++k) {
        const int j = bucket[off + k];
        if (j == i) continue;                // wave-uniform branch
        const float* zj = z + (size_t)j * D_DIM + lane * 8;
        const float4 b0 = *(const float4*)(zj);
        const float4 b1 = *(const float4*)(zj + 4);

        float d, s;
        d = a0.x - b0.x; s  = d * d;
        d = a0.y - b0.y; s += d * d;
        d = a0.z - b0.z; s += d * d;
        d = a0.w - b0.w; s += d * d;
        d = a1.x - b1.x; s += d * d;
        d = a1.y - b1.y; s += d * d;
        d = a1.z - b1.z; s += d * d;
        d = a1.w - b1.w; s += d * d;

        // 64-lane butterfly reduction
        s += __shfl_xor(s, 1,  64);
        s += __shfl_xor(s, 2,  64);
        s += __shfl_xor(s, 4,  64);
        s += __shfl_xor(s, 8,  64);
        s += __shfl_xor(s, 16, 64);
        s += __shfl_xor(s, 32, 64);

        acc += (s > 0.0f) ? sqrtf(s) : 0.0f;
    }

    if (lane == 0) {
        out[i] = (cnt > 1) ? acc / (float)(cnt - 1) : 0.0f;
    }
}

// ---------------- launch ----------------

extern "C" void kernel_launch(void* const* d_in, const int* in_sizes, int n_in,
                              void* d_out, int out_size, void* d_ws, size_t ws_size,
                              hipStream_t stream) {
    const float* z  = (const float*)d_in[0];
    const int*   Mx = (const int*)d_in[1];
    float*       out = (float*)d_out;

    int* counts  = (int*)d_ws;              // [256]
    int* offsets = counts + N_LABELS;       // [256]
    int* bucket  = offsets + N_LABELS;      // [8192]

    count_kernel<<<N_LABELS, 64, 0, stream>>>(Mx, counts);
    scan_kernel<<<1, 64, 0, stream>>>(counts, offsets);
    fill_kernel<<<N_LABELS, 64, 0, stream>>>(Mx, offsets, bucket);

    const int threads = 256;                       // 4 waves per block
    const int blocks  = (B_ROWS * 64) / threads;   // one wave per row
    loss_kernel<<<blocks, threads, 0, stream>>>(z, Mx, counts, offsets, bucket, out);
}